// Round 3
// baseline (374.136 us; speedup 1.0000x reference)
//
#include <hip/hip_runtime.h>

#define N_NODES 50000
#define N_EDGES 800000
// IN_F = 64, OUT_F = 64, EDGE_F = 16, d_in1 = 144
// edge_index arrives as int32[2*E]: src = ei[e], dst = ei[E+e].

typedef __attribute__((ext_vector_type(8))) short bf16x8;  // 8 bf16 = 4 VGPRs
typedef __attribute__((ext_vector_type(4))) float f32x4;

__device__ inline short f2bf(float f) {       // fp32 -> bf16 bits, RNE
    union { float f; unsigned u; } v; v.f = f;
    unsigned r = v.u + 0x7FFFu + ((v.u >> 16) & 1u);
    return (short)(r >> 16);
}

// ---------------------------------------------------------------------------
// pre_kernel: xa = x @ W1[0:64,:], xb = x @ W1[64:128,:]   (fp32, N x 64 each)
// 4 accumulators to break the strict-fp dependent FMA chain.
// ---------------------------------------------------------------------------
__global__ __launch_bounds__(256) void pre_kernel(
    const float* __restrict__ x, const float* __restrict__ W1,
    float* __restrict__ xa, float* __restrict__ xb)
{
    const int w = threadIdx.x >> 6;
    const int j = threadIdx.x & 63;
    const int gw = blockIdx.x * 4 + w;
    const int p = gw & 1;
    const int pair = gw >> 1;
    const int npair = (gridDim.x * 4) >> 1;

    float wc[64];
#pragma unroll
    for (int k = 0; k < 64; ++k) wc[k] = W1[(p * 64 + k) * 64 + j];

    float* __restrict__ outp = p ? xb : xa;

    for (int i = pair; i < N_NODES; i += npair) {
        const float4* xr = (const float4*)&x[(long)i * 64];
        float a0 = 0.f, a1 = 0.f, a2 = 0.f, a3 = 0.f;
#pragma unroll
        for (int k4 = 0; k4 < 16; ++k4) {
            float4 xv = xr[k4];
            a0 += xv.x * wc[k4 * 4 + 0];
            a1 += xv.y * wc[k4 * 4 + 1];
            a2 += xv.z * wc[k4 * 4 + 2];
            a3 += xv.w * wc[k4 * 4 + 3];
        }
        outp[(long)i * 64 + j] = (a0 + a1) + (a2 + a3);
    }
}

// ---------------------------------------------------------------------------
// edge_mfma: per wave-tile of 16 edges,
//   C1(16x64) = EA(16x16, K-padded to 32) @ W1c          -> 4 mfma
//   h = relu(C1 + xa[src] + xb[dst] + b1)  (bf16, via LDS C->A relayout)
//   C2(16x64) = h @ W2                                    -> 8 mfma
//   atomicAdd(out[dst], C2 + b2)
// Persistent waves; W1c/W2 fragments live in registers.
// MFMA layouts (16x16x32 bf16): A: m=lane&15, k=(lane>>4)*8+i
//                               B: n=lane&15, k=(lane>>4)*8+i
//                               C: n=lane&15, m=(lane>>4)*4+r
// ---------------------------------------------------------------------------
__global__ __launch_bounds__(256) void edge_mfma(
    const float* __restrict__ xa, const float* __restrict__ xb,
    const int* __restrict__ ei,
    const float* __restrict__ edge_attr,
    const float* __restrict__ W1, const float* __restrict__ b1,
    const float* __restrict__ W2, const float* __restrict__ b2,
    float* __restrict__ out)
{
    __shared__ __align__(16) unsigned short hbuf[4][16][72];  // bf16, +8 pad

    const int w = threadIdx.x >> 6;
    const int l = threadIdx.x & 63;
    const int n = l & 15;          // C col / A row / B col
    const int q = l >> 4;          // quad

    // --- persistent weight fragments ---
    bf16x8 w1f[4];                 // W1c (rows 128..143), K-padded
    bf16x8 w2f[4][2];              // W2, k-chunks of 32
    float b1v[4], b2v[4];
#pragma unroll
    for (int t = 0; t < 4; ++t) {
        const int col = t * 16 + n;
#pragma unroll
        for (int i = 0; i < 8; ++i) {
            const int k = q * 8 + i;
            w1f[t][i] = (q < 2) ? f2bf(W1[(128 + k) * 64 + col]) : (short)0;
            w2f[t][0][i] = f2bf(W2[k * 64 + col]);
            w2f[t][1][i] = f2bf(W2[(32 + k) * 64 + col]);
        }
        b1v[t] = b1[col];
        b2v[t] = b2[col];
    }

    const int nwaves = gridDim.x * 4;
    const int gw = blockIdx.x * 4 + w;

    for (int tile = gw; tile < N_EDGES / 16; tile += nwaves) {
        const long eb = (long)tile * 16;

        // edge indices: lanes 0..15 = src, 16..31 = dst
        int idxv = 0;
        if (l < 16)       idxv = ei[eb + l];
        else if (l < 32)  idxv = ei[(long)N_EDGES + eb + (l - 16)];

        int srcr[4], dstr[4];      // node ids for this quad's 4 C rows
#pragma unroll
        for (int r = 0; r < 4; ++r) {
            srcr[r] = __shfl(idxv, q * 4 + r);
            dstr[r] = __shfl(idxv, 16 + q * 4 + r);
        }

        // edge_attr A-fragment (K padded: quads 2,3 are zero)
        bf16x8 eaf;
        if (q < 2) {
            const float* ep = &edge_attr[(eb + n) * 16 + q * 8];
            float4 e0 = *(const float4*)ep;
            float4 e1 = *(const float4*)(ep + 4);
            eaf[0] = f2bf(e0.x); eaf[1] = f2bf(e0.y);
            eaf[2] = f2bf(e0.z); eaf[3] = f2bf(e0.w);
            eaf[4] = f2bf(e1.x); eaf[5] = f2bf(e1.y);
            eaf[6] = f2bf(e1.z); eaf[7] = f2bf(e1.w);
        } else {
#pragma unroll
            for (int i = 0; i < 8; ++i) eaf[i] = (short)0;
        }

        // GEMM1c
        f32x4 c1[4];
#pragma unroll
        for (int t = 0; t < 4; ++t) {
            f32x4 z = {0.f, 0.f, 0.f, 0.f};
            c1[t] = __builtin_amdgcn_mfma_f32_16x16x32_bf16(eaf, w1f[t], z, 0, 0, 0);
        }

        // gather xa[src]+xb[dst] in C layout (two-phase for load ILP)
        float g[4][4];
#pragma unroll
        for (int t = 0; t < 4; ++t)
#pragma unroll
            for (int r = 0; r < 4; ++r)
                g[t][r] = xa[(long)srcr[r] * 64 + t * 16 + n]
                        + xb[(long)dstr[r] * 64 + t * 16 + n];

        // epilogue: h = relu(c1 + g + b1) -> bf16 -> LDS (C layout write)
#pragma unroll
        for (int t = 0; t < 4; ++t)
#pragma unroll
            for (int r = 0; r < 4; ++r) {
                float h = fmaxf(c1[t][r] + g[t][r] + b1v[t], 0.f);
                hbuf[w][q * 4 + r][t * 16 + n] = (unsigned short)f2bf(h);
            }

        // read h as A-fragments (wave-internal; lgkmcnt orders write->read)
        bf16x8 hf0 = *(const bf16x8*)&hbuf[w][n][q * 8];
        bf16x8 hf1 = *(const bf16x8*)&hbuf[w][n][32 + q * 8];

        // GEMM2
        f32x4 c2[4];
#pragma unroll
        for (int t = 0; t < 4; ++t) {
            f32x4 z = {0.f, 0.f, 0.f, 0.f};
            c2[t] = __builtin_amdgcn_mfma_f32_16x16x32_bf16(hf0, w2f[t][0], z, 0, 0, 0);
            c2[t] = __builtin_amdgcn_mfma_f32_16x16x32_bf16(hf1, w2f[t][1], c2[t], 0, 0, 0);
        }

        // scatter
#pragma unroll
        for (int t = 0; t < 4; ++t)
#pragma unroll
            for (int r = 0; r < 4; ++r)
                unsafeAtomicAdd(&out[(long)dstr[r] * 64 + t * 16 + n],
                                c2[t][r] + b2v[t]);
    }
}

// ---------------------------------------------------------------------------
// fallback (only if ws too small): one wave per edge, full 144-dot, shfl GEMM2
// ---------------------------------------------------------------------------
__global__ __launch_bounds__(256) void fallback_kernel(
    const float* __restrict__ x, const int* __restrict__ ei,
    const float* __restrict__ edge_attr,
    const float* __restrict__ W1, const float* __restrict__ b1,
    const float* __restrict__ W2, const float* __restrict__ b2,
    float* __restrict__ out)
{
    const int w = threadIdx.x >> 6;
    const int j = threadIdx.x & 63;
    const long e = (long)blockIdx.x * 4 + w;
    if (e >= N_EDGES) return;
    const int s  = ei[e];
    const int dd = ei[(long)N_EDGES + e];

    float acc = b1[j];
    for (int k = 0; k < 64; ++k) acc += x[(long)s  * 64 + k] * W1[k * 64 + j];
    for (int k = 0; k < 64; ++k) acc += x[(long)dd * 64 + k] * W1[(64 + k) * 64 + j];
    for (int k = 0; k < 16; ++k) acc += edge_attr[e * 16 + k] * W1[(128 + k) * 64 + j];
    const float h = fmaxf(acc, 0.f);

    float msg = b2[j];
    for (int k = 0; k < 64; ++k) msg += __shfl(h, k) * W2[k * 64 + j];
    unsafeAtomicAdd(&out[(long)dd * 64 + j], msg);
}

extern "C" void kernel_launch(void* const* d_in, const int* in_sizes, int n_in,
                              void* d_out, int out_size, void* d_ws, size_t ws_size,
                              hipStream_t stream) {
    const float* x   = (const float*)d_in[0];
    const int*   ei  = (const int*)d_in[1];
    const float* ea  = (const float*)d_in[2];
    const float* W1  = (const float*)d_in[3];
    const float* b1  = (const float*)d_in[4];
    const float* W2  = (const float*)d_in[5];
    const float* b2  = (const float*)d_in[6];
    float* out = (float*)d_out;

    hipMemsetAsync(out, 0, (size_t)N_NODES * 64 * sizeof(float), stream);

    const size_t need = (size_t)2 * N_NODES * 64 * sizeof(float);
    if (ws_size >= need) {
        float* xauf = (float*)d_ws;
        float* xbuf = xauf + (size_t)N_NODES * 64;
        pre_kernel<<<1024, 256, 0, stream>>>(x, W1, xauf, xbuf);
        edge_mfma<<<1024, 256, 0, stream>>>(xauf, xbuf, ei, ea,
                                            W1, b1, W2, b2, out);
    } else {
        fallback_kernel<<<N_EDGES / 4, 256, 0, stream>>>(x, ei, ea,
                                                         W1, b1, W2, b2, out);
    }
}